// Round 11
// baseline (412.737 us; speedup 1.0000x reference)
//
#include <hip/hip_runtime.h>

namespace {

constexpr int kB = 8, kCin = 2, kBins = 1024, kFrames = 512;
constexpr int kC = 8, kE = 1024, kN = kB * kFrames; // 4096

typedef _Float16 f16x8 __attribute__((ext_vector_type(8)));
typedef float f32x4 __attribute__((ext_vector_type(4)));

union HPack4 { _Float16 h[4]; uint2 u; };

// split v = h + (l/4096), h/l normal-range f16 (denormal-proof)
__device__ inline void splitf(float v, _Float16& h, _Float16& l) {
    float a = (fabsf(v) >= 6.103515625e-05f) ? v : 0.f;
    _Float16 hh = (_Float16)a;
    h = hh;
    l = (_Float16)((v - (float)hh) * 4096.0f);
}

// ================= conv v2b: v2 minus vbuf retile (direct stores) ==========
// Identical arithmetic and store addresses to r7-proven v2 -> v bit-identical.
// 8B-per-thread stores merge to full 64B lines in L2 (r8 measured: no write
// amplification). Barriers 26 -> 3.
constexpr int BT = 32, FT = 32, XB = BT + 16, HB = BT + 8;

__global__ __launch_bounds__(256) void conv_fused_v2b(
    const float* __restrict__ x,
    const float* __restrict__ w1, const float* __restrict__ b1,
    const float* __restrict__ w2, const float* __restrict__ b2,
    const float* __restrict__ wsk, const float* __restrict__ bsk,
    _Float16* __restrict__ V1, float* __restrict__ partials)
{
    __shared__ float xt[kCin][XB][33];
    __shared__ float h1t[kC][HB][33];
    __shared__ float w1s[kC * kCin * 9];
    __shared__ float w2s[kC * kC][12];
    __shared__ float wsks[kC * kCin];
    __shared__ float b1s[kC], b2s[kC], bsks[kC];
    __shared__ float reds[4];

    const int t = threadIdx.x;
    const int bt = blockIdx.x, ft = blockIdx.y, bb = blockIdx.z;
    const int bs = bt * BT, f0 = ft * FT;
    _Float16* V2 = V1 + (size_t)33554432;

    for (int i = t; i < kC * kCin * 9; i += 256) w1s[i] = w1[i];
    for (int i = t; i < 768; i += 256) {
        int cc = i / 12, k = i % 12;
        w2s[cc][k] = (k < 9) ? w2[cc * 9 + k] : 0.f;
    }
    if (t < kC * kCin) wsks[t] = wsk[t];
    if (t < kC) { b1s[t] = b1[t]; b2s[t] = b2[t]; bsks[t] = bsk[t]; }

    // stage x tile [bs-8, bs+40)
    for (int i = t; i < kCin * XB * FT; i += 256) {
        int fi = i % FT, xb = (i / FT) % XB, ci = i / (FT * XB);
        int gb = bs - 8 + xb;
        float v = 0.f;
        if (gb >= 0 && gb < kBins)
            v = x[((bb * kCin + ci) * kBins + gb) * kFrames + f0 + fi];
        xt[ci][xb][fi] = v;
    }
    __syncthreads();

    const int fi = t & 31;
    const int r = t >> 5; // 0..7

    // h1 stage (verbatim v2)
    for (int q = 0; q < 5; q++) {
        float a8[8];
        #pragma unroll
        for (int jj = 0; jj < 8; jj++) a8[jj] = b1s[r];
        #pragma unroll
        for (int ci = 0; ci < kCin; ci++) {
            float w[16];
            #pragma unroll
            for (int k = 0; k < 16; k++) w[k] = xt[ci][q * 8 + k][fi];
            const float* wp = &w1s[(r * kCin + ci) * 9];
            #pragma unroll
            for (int jj = 0; jj < 8; jj++)
                #pragma unroll
                for (int k = 0; k < 9; k++)
                    a8[jj] += w[jj + k] * wp[k];
        }
        #pragma unroll
        for (int jj = 0; jj < 8; jj++) {
            int hb = q * 8 + jj;
            int gb = bs - 4 + hb;
            float v = (gb >= 0 && gb < kBins) ? (a8[jj] > 0.f ? a8[jj] : 0.2f * a8[jj]) : 0.f;
            h1t[r][hb][fi] = v;
        }
    }
    __syncthreads();

    // main stage (verbatim v2): thread (fi, r) -> 8 c x 4 bins (ob=r*4+j)
    float acc[8][4];
    #pragma unroll
    for (int c = 0; c < 8; c++)
        #pragma unroll
        for (int j = 0; j < 4; j++) acc[c][j] = b2s[c] + bsks[c];

    for (int ci = 0; ci < 8; ci++) {
        float w[12];
        #pragma unroll
        for (int k = 0; k < 12; k++) w[k] = h1t[ci][r * 4 + k][fi];
        #pragma unroll
        for (int c = 0; c < 8; c++) {
            const float4* wp4 = (const float4*)&w2s[c * 8 + ci][0];
            float4 wA = wp4[0], wB = wp4[1], wC = wp4[2];
            float wk[9] = {wA.x, wA.y, wA.z, wA.w, wB.x, wB.y, wB.z, wB.w, wC.x};
            #pragma unroll
            for (int j = 0; j < 4; j++) {
                float s = 0.f;
                #pragma unroll
                for (int k = 0; k < 9; k++) s += w[j + k] * wk[k];
                acc[c][j] += s;
            }
        }
    }
    // skip path (verbatim v2)
    #pragma unroll
    for (int j = 0; j < 4; j++) {
        float x0 = xt[0][r * 4 + j + 8][fi];
        float x1 = xt[1][r * 4 + j + 8][fi];
        #pragma unroll
        for (int c = 0; c < 8; c++)
            acc[c][j] += x0 * wsks[c * 2] + x1 * wsks[c * 2 + 1];
    }

    float sq = 0.f;
    #pragma unroll
    for (int c = 0; c < 8; c++)
        #pragma unroll
        for (int j = 0; j < 4; j++) sq += acc[c][j] * acc[c][j];

    // direct stores: same values, same addresses as v2's vbuf path
    const int n = bb * kFrames + f0 + fi;
    #pragma unroll
    for (int c = 0; c < 8; c++) {
        HPack4 ph, pl;
        #pragma unroll
        for (int j = 0; j < 4; j++) splitf(acc[c][j], ph.h[j], pl.h[j]);
        const size_t off = ((size_t)(c * kN + n)) * kBins + bs + r * 4;
        *(uint2*)&V1[off] = ph.u;
        *(uint2*)&V2[off] = pl.u;
    }

    // per-block sum(v^2): wave shfl-reduce, then 4-way LDS merge
    #pragma unroll
    for (int off = 32; off > 0; off >>= 1) sq += __shfl_down(sq, off);
    if ((t & 63) == 0) reds[t >> 6] = sq;
    __syncthreads();
    if (t == 0) {
        int blin = (bb * gridDim.y + blockIdx.y) * gridDim.x + blockIdx.x;
        partials[blin] = reds[0] + reds[1] + reds[2] + reds[3];
    }
}

// ================= codebook split + e2 (+ pk init) =================
__global__ __launch_bounds__(256) void cbsplit_e2(
    const float* __restrict__ cb, _Float16* __restrict__ B1,
    float* __restrict__ e2, unsigned long long* __restrict__ pk)
{
    const int gid = blockIdx.x * 256 + threadIdx.x;
    if (gid < kC * kN) pk[gid] = ~0ull;

    const int gw = gid >> 6;
    const int lane = threadIdx.x & 63;
    _Float16* B2 = B1 + (size_t)8388608;
    const float* row = cb + (size_t)gw * kBins;
    float s = 0.f;
    #pragma unroll
    for (int j = 0; j < 4; j++) {
        float4 v = *(const float4*)&row[lane * 4 + j * 256];
        s += v.x * v.x + v.y * v.y + v.z * v.z + v.w * v.w;
        HPack4 ph, pl;
        splitf(v.x, ph.h[0], pl.h[0]);
        splitf(v.y, ph.h[1], pl.h[1]);
        splitf(v.z, ph.h[2], pl.h[2]);
        splitf(v.w, ph.h[3], pl.h[3]);
        size_t off = (size_t)gw * kBins + lane * 4 + j * 256;
        *(uint2*)&B1[off] = ph.u;
        *(uint2*)&B2[off] = pl.u;
    }
    #pragma unroll
    for (int off = 32; off > 0; off >>= 1) s += __shfl_down(s, off);
    if (lane == 0) e2[gw] = s;
}

// ================= MFMA distance + argmin (r10-proven, verbatim) ===========
__global__ __launch_bounds__(512, 2) void dist_mfma(
    const _Float16* __restrict__ V1, const _Float16* __restrict__ B1p,
    const float* __restrict__ e2, unsigned long long* __restrict__ pk)
{
    __shared__ char smem[3 * 49152 + 2048];

    const int t = threadIdx.x;
    const int bidx = blockIdx.x;
    const int ch = bidx & 7;
    const int eh = (bidx >> 3) & 1;
    const int n0 = (bidx >> 4) * 256;
    const int w = t >> 6, lane = t & 63;
    const int l15 = lane & 15, kc4 = lane >> 4;
    const int wm = w >> 1, we = w & 1;

    float* lds_e2 = (float*)(smem + 147456);
    lds_e2[t] = e2[ch * kE + eh * 512 + t];

    const _Float16* srcA[4];
    int dstA[4];
    #pragma unroll
    for (int i = 0; i < 4; i++) {
        int ci = i * 512 + t;
        int row = ci >> 3, slot = ci & 7;
        int g = slot ^ (row & 7);
        int p = g >> 2, kc = g & 3;
        srcA[i] = V1 + (size_t)p * 33554432 + ((size_t)(ch * kN + n0 + row)) * kBins + kc * 8;
        dstA[i] = ci * 16;
    }
    const _Float16* srcB[2];
    int dstB[2];
    #pragma unroll
    for (int i = 0; i < 2; i++) {
        int bi = i * 512 + t;
        int row = bi >> 3, slot = bi & 7;
        int g = slot ^ (row & 7);
        int p = g >> 2, kc = g & 3;
        srcB[i] = B1p + (size_t)p * 8388608 + ((size_t)(ch * kE + row)) * kBins + kc * 8;
        dstB[i] = 32768 + bi * 16;
    }

    const int rowA = wm * 64 + l15;
    const int rowB = we * 64 + l15;
    const int baseA1 = rowA * 128 + ((kc4) ^ (rowA & 7)) * 16;
    const int baseA2 = rowA * 128 + ((4 + kc4) ^ (rowA & 7)) * 16;
    const int baseB1 = 32768 + rowB * 128 + ((kc4) ^ (rowB & 7)) * 16;
    const int baseB2 = 32768 + rowB * 128 + ((4 + kc4) ^ (rowB & 7)) * 16;

    float rm[16];
    int ri[16];
    #pragma unroll
    for (int s = 0; s < 16; s++) { rm[s] = 3.4e38f; ri[s] = 0; }

    typedef const __attribute__((address_space(1))) void gsrc_t;
    typedef __attribute__((address_space(3))) void gdst_t;

    auto issue = [&](int jj, int bw) {
        const int k0 = (jj & 31) * 32;
        const size_t etoff = (size_t)(eh * 4 + (jj >> 5)) * 128 * kBins + k0;
        char* nb = smem + bw * 49152;
        #pragma unroll
        for (int i = 0; i < 4; i++)
            __builtin_amdgcn_global_load_lds((gsrc_t*)(srcA[i] + k0), (gdst_t*)(nb + dstA[i]), 16, 0, 0);
        #pragma unroll
        for (int i = 0; i < 2; i++)
            __builtin_amdgcn_global_load_lds((gsrc_t*)(srcB[i] + etoff), (gdst_t*)(nb + dstB[i]), 16, 0, 0);
    };

    __syncthreads();

    issue(0, 0);
    issue(1, 1);
    int bread = 0, bwrite = 2;

    #pragma unroll 1
    for (int et = 0; et < 4; et++) {
        f32x4 hi[4][4], lo[4][4];
        #pragma unroll
        for (int mi = 0; mi < 4; mi++)
            #pragma unroll
            for (int ei = 0; ei < 4; ei++) {
                hi[mi][ei] = (f32x4){0.f, 0.f, 0.f, 0.f};
                lo[mi][ei] = (f32x4){0.f, 0.f, 0.f, 0.f};
            }

        #pragma unroll 1
        for (int ks = 0; ks < 32; ks++) {
            const int j = et * 32 + ks;
            if (j < 127)
                asm volatile("s_waitcnt vmcnt(6)\n\ts_barrier" ::: "memory");
            else
                asm volatile("s_waitcnt vmcnt(0)\n\ts_barrier" ::: "memory");
            if (j < 126) {
                issue(j + 2, bwrite);
                bwrite = (bwrite == 2) ? 0 : bwrite + 1;
            }

            const char* buf = smem + bread * 49152;
            bread = (bread == 2) ? 0 : bread + 1;

            f16x8 a1[4], a2[4], b1f[4], b2f[4];
            #pragma unroll
            for (int mi = 0; mi < 4; mi++) {
                a1[mi] = *(const f16x8*)(buf + baseA1 + mi * 2048);
                a2[mi] = *(const f16x8*)(buf + baseA2 + mi * 2048);
            }
            #pragma unroll
            for (int ei = 0; ei < 4; ei++) {
                b1f[ei] = *(const f16x8*)(buf + baseB1 + ei * 2048);
                b2f[ei] = *(const f16x8*)(buf + baseB2 + ei * 2048);
            }
            __builtin_amdgcn_s_setprio(1);
            #pragma unroll
            for (int mi = 0; mi < 4; mi++)
                #pragma unroll
                for (int ei = 0; ei < 4; ei++) {
                    hi[mi][ei] = __builtin_amdgcn_mfma_f32_16x16x32_f16(a1[mi], b1f[ei], hi[mi][ei], 0, 0, 0);
                    lo[mi][ei] = __builtin_amdgcn_mfma_f32_16x16x32_f16(a1[mi], b2f[ei], lo[mi][ei], 0, 0, 0);
                    lo[mi][ei] = __builtin_amdgcn_mfma_f32_16x16x32_f16(a2[mi], b1f[ei], lo[mi][ei], 0, 0, 0);
                }
            __builtin_amdgcn_s_setprio(0);
        }

        #pragma unroll
        for (int ei = 0; ei < 4; ei++) {
            const int eloc = et * 128 + we * 64 + ei * 16 + l15;
            const float ev = lds_e2[eloc];
            const int eix = eh * 512 + eloc;
            #pragma unroll
            for (int mi = 0; mi < 4; mi++) {
                f32x4 dot4 = hi[mi][ei] + lo[mi][ei] * (1.0f / 4096.0f);
                #pragma unroll
                for (int rr = 0; rr < 4; rr++) {
                    float d = ev - 2.0f * dot4[rr];
                    int s = mi * 4 + rr;
                    if (d < rm[s]) { rm[s] = d; ri[s] = eix; }
                }
            }
        }
    }

    #pragma unroll
    for (int m = 1; m < 16; m <<= 1) {
        #pragma unroll
        for (int s = 0; s < 16; s++) {
            float ov = __shfl_xor(rm[s], m);
            int oi = __shfl_xor(ri[s], m);
            if (ov < rm[s] || (ov == rm[s] && oi < ri[s])) { rm[s] = ov; ri[s] = oi; }
        }
    }

    float* mv = (float*)smem;           // [256][2]
    int* miv = (int*)(smem + 2048);     // [256][2]
    __syncthreads();
    if (l15 == 0) {
        #pragma unroll
        for (int s = 0; s < 16; s++) {
            int mi = s >> 2, rr = s & 3;
            int rloc = wm * 64 + mi * 16 + (lane >> 4) * 4 + rr;
            mv[rloc * 2 + we] = rm[s];
            miv[rloc * 2 + we] = ri[s];
        }
    }
    __syncthreads();
    if (t < 256) {
        float v0 = mv[t * 2], v1 = mv[t * 2 + 1];
        int i0 = miv[t * 2], i1 = miv[t * 2 + 1];
        bool take1 = (v1 < v0) || (v1 == v0 && i1 < i0);
        float bv = take1 ? v1 : v0;
        int bi = take1 ? i1 : i0;
        unsigned int u = __float_as_uint(bv);
        unsigned int su = (u & 0x80000000u) ? ~u : (u ^ 0x80000000u);
        unsigned long long packed = ((unsigned long long)su << 32) | (unsigned int)bi;
        atomicMin(&pk[ch * kN + n0 + t], packed);
    }
}

// ================= gather (cp-XCD affine) + fused loss =====================
__global__ __launch_bounds__(256) void gather_pk(
    const float* __restrict__ cb, const unsigned long long* __restrict__ pk,
    const float* __restrict__ partials, float* __restrict__ out,
    float* __restrict__ loss)
{
    const int t = threadIdx.x;
    const int lane = t & 63, q = t >> 6;
    const int b = blockIdx.x;
    const int cp = b & 7;
    const int bt = (b >> 3) & 63;
    const int ftile = (b >> 9) & 7;
    const int bb = b >> 12;
    const int co = (kC - 1) - cp;
    const int f = ftile * 64 + lane;
    const int n = bb * kFrames + f;
    const int e = (int)(unsigned int)(pk[cp * kN + n] & 0xFFFFFFFFull);
    const int bin0 = bt * 16 + q * 4;
    const float4 v4 = *(const float4*)&cb[((size_t)cp * kE + e) * kBins + bin0];
    const size_t base = ((size_t)(bb * kC + co) * kBins + bin0) * kFrames + f;
    out[base] = v4.x;
    out[base + kFrames] = v4.y;
    out[base + 2 * (size_t)kFrames] = v4.z;
    out[base + 3 * (size_t)kFrames] = v4.w;

    if (b == 32767) {
        __shared__ float reds[256];
        float s = 0.f;
        for (int i = t; i < kC * kN; i += 256) {
            unsigned int su = (unsigned int)(pk[i] >> 32);
            unsigned int u = (su & 0x80000000u) ? (su ^ 0x80000000u) : ~su;
            s += __uint_as_float(u);
        }
        for (int i = t; i < 4096; i += 256) s += partials[i];
        reds[t] = s;
        __syncthreads();
        for (int off = 128; off > 0; off >>= 1) {
            if (t < off) reds[t] += reds[t + off];
            __syncthreads();
        }
        if (t == 0) loss[0] = 1.25f * reds[0] / (float)(kN * kBins);
    }
}

} // namespace

extern "C" void kernel_launch(void* const* d_in, const int* in_sizes, int n_in,
                              void* d_out, int out_size, void* d_ws, size_t ws_size,
                              hipStream_t stream)
{
    const float* x   = (const float*)d_in[0];
    const float* w1  = (const float*)d_in[1];
    const float* b1  = (const float*)d_in[2];
    const float* w2  = (const float*)d_in[3];
    const float* b2  = (const float*)d_in[4];
    const float* wsk = (const float*)d_in[5];
    const float* bsk = (const float*)d_in[6];
    const float* cb  = (const float*)d_in[7];
    float* out = (float*)d_out;
    char* ws = (char*)d_ws;

    // ws layout: B1|B2 32M | e2 32K | pk 256K | partials 16K
    _Float16* B1 = (_Float16*)ws;
    float* e2                  = (float*)(ws + 33554432);
    unsigned long long* pk     = (unsigned long long*)(ws + 33554432 + 32768);
    float* partials            = (float*)(ws + 33554432 + 32768 + 262144);
    _Float16* V1 = (_Float16*)d_out; // V1 67MB | V2 67MB, overwritten by gather

    conv_fused_v2b<<<dim3(kBins / BT, kFrames / FT, kB), 256, 0, stream>>>(
        x, w1, b1, w2, b2, wsk, bsk, V1, partials);
    cbsplit_e2<<<(kC * kE) / 4, 256, 0, stream>>>(cb, B1, e2, pk);
    dist_mfma<<<dim3(256), 512, 0, stream>>>(V1, B1, e2, pk);
    gather_pk<<<dim3(32768), 256, 0, stream>>>(cb, pk, partials, out,
                                               out + (size_t)kC * kBins * kN);
}

// Round 12
// 411.203 us; speedup vs baseline: 1.0037x; 1.0037x over previous
//
#include <hip/hip_runtime.h>

namespace {

constexpr int kB = 8, kCin = 2, kBins = 1024, kFrames = 512;
constexpr int kC = 8, kE = 1024, kN = kB * kFrames; // 4096

typedef _Float16 f16x8 __attribute__((ext_vector_type(8)));
typedef float f32x4 __attribute__((ext_vector_type(4)));

union HPack4 { _Float16 h[4]; uint2 u; };
union HPack2 { _Float16 h[2]; unsigned int u; };

// split v = h + (l/4096), h/l normal-range f16 (denormal-proof)
__device__ inline void splitf(float v, _Float16& h, _Float16& l) {
    float a = (fabsf(v) >= 6.103515625e-05f) ? v : 0.f;
    _Float16 hh = (_Float16)a;
    h = hh;
    l = (_Float16)((v - (float)hh) * 4096.0f);
}

// ================= conv v2c: v2b arithmetic, 512-thread blocks =============
// Same 58.9KB LDS, same tile (BT=32 bins x FT=32 frames x batch), but 512
// threads -> 2 blocks/CU = 16 waves/CU (4/SIMD), doubling TLP for the
// latency-bound h1/main chains. Thread (fi=t&31, r=t>>5 in 0..15): h1 stage
// cm=r&7 with octets split by rh=r>>3 (wave-uniform); main stage 8c x 2 bins
// (ob=r*2+j). Per-output FP chains identical to v2 -> v bit-identical.
constexpr int BT = 32, FT = 32, XB = BT + 16, HB = BT + 8;

__global__ __launch_bounds__(512, 4) void conv_fused_v2c(
    const float* __restrict__ x,
    const float* __restrict__ w1, const float* __restrict__ b1,
    const float* __restrict__ w2, const float* __restrict__ b2,
    const float* __restrict__ wsk, const float* __restrict__ bsk,
    _Float16* __restrict__ V1, float* __restrict__ partials)
{
    __shared__ float xt[kCin][XB][33];
    __shared__ float h1t[kC][HB][33];
    __shared__ float w1s[kC * kCin * 9];
    __shared__ float w2s[kC * kC][12];
    __shared__ float wsks[kC * kCin];
    __shared__ float b1s[kC], b2s[kC], bsks[kC];
    __shared__ float reds[8];

    const int t = threadIdx.x;
    const int bt = blockIdx.x, ft = blockIdx.y, bb = blockIdx.z;
    const int bs = bt * BT, f0 = ft * FT;
    _Float16* V2 = V1 + (size_t)33554432;

    if (t < kC * kCin * 9) w1s[t] = w1[t];
    for (int i = t; i < 768; i += 512) {
        int cc = i / 12, k = i % 12;
        w2s[cc][k] = (k < 9) ? w2[cc * 9 + k] : 0.f;
    }
    if (t < kC * kCin) wsks[t] = wsk[t];
    if (t < kC) { b1s[t] = b1[t]; b2s[t] = b2[t]; bsks[t] = bsk[t]; }

    // stage x tile [bs-8, bs+40)
    for (int i = t; i < kCin * XB * FT; i += 512) {
        int fi = i % FT, xb = (i / FT) % XB, ci = i / (FT * XB);
        int gb = bs - 8 + xb;
        float v = 0.f;
        if (gb >= 0 && gb < kBins)
            v = x[((bb * kCin + ci) * kBins + gb) * kFrames + f0 + fi];
        xt[ci][xb][fi] = v;
    }
    __syncthreads();

    const int fi = t & 31;
    const int r = t >> 5;          // 0..15
    const int cm = r & 7, rh = r >> 3;  // rh wave-uniform (waves 0-3: 0, 4-7: 1)

    // h1 stage: octets q in {0,2,4} for rh=0, {1,3} for rh=1 (partition of 0..4)
    #pragma unroll
    for (int qi = 0; qi < 3; qi++) {
        const int q = qi * 2 + rh;
        if (q < 5) {
            float a8[8];
            #pragma unroll
            for (int jj = 0; jj < 8; jj++) a8[jj] = b1s[cm];
            #pragma unroll
            for (int ci = 0; ci < kCin; ci++) {
                float w[16];
                #pragma unroll
                for (int k = 0; k < 16; k++) w[k] = xt[ci][q * 8 + k][fi];
                const float* wp = &w1s[(cm * kCin + ci) * 9];
                #pragma unroll
                for (int jj = 0; jj < 8; jj++)
                    #pragma unroll
                    for (int k = 0; k < 9; k++)
                        a8[jj] += w[jj + k] * wp[k];
            }
            #pragma unroll
            for (int jj = 0; jj < 8; jj++) {
                int hb = q * 8 + jj;
                int gb = bs - 4 + hb;
                float v = (gb >= 0 && gb < kBins) ? (a8[jj] > 0.f ? a8[jj] : 0.2f * a8[jj]) : 0.f;
                h1t[cm][hb][fi] = v;
            }
        }
    }
    __syncthreads();

    // main stage: thread (fi, r) -> 8 c x 2 bins (ob = r*2 + j)
    float acc[8][2];
    #pragma unroll
    for (int c = 0; c < 8; c++)
        #pragma unroll
        for (int j = 0; j < 2; j++) acc[c][j] = b2s[c] + bsks[c];

    for (int ci = 0; ci < 8; ci++) {
        float w[10];
        #pragma unroll
        for (int k = 0; k < 10; k++) w[k] = h1t[ci][r * 2 + k][fi];
        #pragma unroll
        for (int c = 0; c < 8; c++) {
            const float4* wp4 = (const float4*)&w2s[c * 8 + ci][0];
            float4 wA = wp4[0], wB = wp4[1], wC = wp4[2];
            float wk[9] = {wA.x, wA.y, wA.z, wA.w, wB.x, wB.y, wB.z, wB.w, wC.x};
            #pragma unroll
            for (int j = 0; j < 2; j++) {
                float s = 0.f;
                #pragma unroll
                for (int k = 0; k < 9; k++) s += w[j + k] * wk[k];
                acc[c][j] += s;
            }
        }
    }
    // skip path
    #pragma unroll
    for (int j = 0; j < 2; j++) {
        float x0 = xt[0][r * 2 + j + 8][fi];
        float x1 = xt[1][r * 2 + j + 8][fi];
        #pragma unroll
        for (int c = 0; c < 8; c++)
            acc[c][j] += x0 * wsks[c * 2] + x1 * wsks[c * 2 + 1];
    }

    float sq = 0.f;
    #pragma unroll
    for (int c = 0; c < 8; c++)
        #pragma unroll
        for (int j = 0; j < 2; j++) sq += acc[c][j] * acc[c][j];

    // direct stores: 2 f16 per (c, plane); 16 r-threads cover each 64B line
    const int n = bb * kFrames + f0 + fi;
    #pragma unroll
    for (int c = 0; c < 8; c++) {
        HPack2 ph, pl;
        splitf(acc[c][0], ph.h[0], pl.h[0]);
        splitf(acc[c][1], ph.h[1], pl.h[1]);
        const size_t off = ((size_t)(c * kN + n)) * kBins + bs + r * 2;
        *(unsigned int*)&V1[off] = ph.u;
        *(unsigned int*)&V2[off] = pl.u;
    }

    // per-block sum(v^2): wave shfl-reduce, then 8-way LDS merge
    #pragma unroll
    for (int off = 32; off > 0; off >>= 1) sq += __shfl_down(sq, off);
    if ((t & 63) == 0) reds[t >> 6] = sq;
    __syncthreads();
    if (t == 0) {
        float s = 0.f;
        #pragma unroll
        for (int i = 0; i < 8; i++) s += reds[i];
        int blin = (bb * gridDim.y + blockIdx.y) * gridDim.x + blockIdx.x;
        partials[blin] = s;
    }
}

// ================= codebook split + e2 (+ pk init) =================
__global__ __launch_bounds__(256) void cbsplit_e2(
    const float* __restrict__ cb, _Float16* __restrict__ B1,
    float* __restrict__ e2, unsigned long long* __restrict__ pk)
{
    const int gid = blockIdx.x * 256 + threadIdx.x;
    if (gid < kC * kN) pk[gid] = ~0ull;

    const int gw = gid >> 6;
    const int lane = threadIdx.x & 63;
    _Float16* B2 = B1 + (size_t)8388608;
    const float* row = cb + (size_t)gw * kBins;
    float s = 0.f;
    #pragma unroll
    for (int j = 0; j < 4; j++) {
        float4 v = *(const float4*)&row[lane * 4 + j * 256];
        s += v.x * v.x + v.y * v.y + v.z * v.z + v.w * v.w;
        HPack4 ph, pl;
        splitf(v.x, ph.h[0], pl.h[0]);
        splitf(v.y, ph.h[1], pl.h[1]);
        splitf(v.z, ph.h[2], pl.h[2]);
        splitf(v.w, ph.h[3], pl.h[3]);
        size_t off = (size_t)gw * kBins + lane * 4 + j * 256;
        *(uint2*)&B1[off] = ph.u;
        *(uint2*)&B2[off] = pl.u;
    }
    #pragma unroll
    for (int off = 32; off > 0; off >>= 1) s += __shfl_down(s, off);
    if (lane == 0) e2[gw] = s;
}

// ================= MFMA distance + argmin (r10-proven, verbatim) ===========
__global__ __launch_bounds__(512, 2) void dist_mfma(
    const _Float16* __restrict__ V1, const _Float16* __restrict__ B1p,
    const float* __restrict__ e2, unsigned long long* __restrict__ pk)
{
    __shared__ char smem[3 * 49152 + 2048];

    const int t = threadIdx.x;
    const int bidx = blockIdx.x;
    const int ch = bidx & 7;
    const int eh = (bidx >> 3) & 1;
    const int n0 = (bidx >> 4) * 256;
    const int w = t >> 6, lane = t & 63;
    const int l15 = lane & 15, kc4 = lane >> 4;
    const int wm = w >> 1, we = w & 1;

    float* lds_e2 = (float*)(smem + 147456);
    lds_e2[t] = e2[ch * kE + eh * 512 + t];

    const _Float16* srcA[4];
    int dstA[4];
    #pragma unroll
    for (int i = 0; i < 4; i++) {
        int ci = i * 512 + t;
        int row = ci >> 3, slot = ci & 7;
        int g = slot ^ (row & 7);
        int p = g >> 2, kc = g & 3;
        srcA[i] = V1 + (size_t)p * 33554432 + ((size_t)(ch * kN + n0 + row)) * kBins + kc * 8;
        dstA[i] = ci * 16;
    }
    const _Float16* srcB[2];
    int dstB[2];
    #pragma unroll
    for (int i = 0; i < 2; i++) {
        int bi = i * 512 + t;
        int row = bi >> 3, slot = bi & 7;
        int g = slot ^ (row & 7);
        int p = g >> 2, kc = g & 3;
        srcB[i] = B1p + (size_t)p * 8388608 + ((size_t)(ch * kE + row)) * kBins + kc * 8;
        dstB[i] = 32768 + bi * 16;
    }

    const int rowA = wm * 64 + l15;
    const int rowB = we * 64 + l15;
    const int baseA1 = rowA * 128 + ((kc4) ^ (rowA & 7)) * 16;
    const int baseA2 = rowA * 128 + ((4 + kc4) ^ (rowA & 7)) * 16;
    const int baseB1 = 32768 + rowB * 128 + ((kc4) ^ (rowB & 7)) * 16;
    const int baseB2 = 32768 + rowB * 128 + ((4 + kc4) ^ (rowB & 7)) * 16;

    float rm[16];
    int ri[16];
    #pragma unroll
    for (int s = 0; s < 16; s++) { rm[s] = 3.4e38f; ri[s] = 0; }

    typedef const __attribute__((address_space(1))) void gsrc_t;
    typedef __attribute__((address_space(3))) void gdst_t;

    auto issue = [&](int jj, int bw) {
        const int k0 = (jj & 31) * 32;
        const size_t etoff = (size_t)(eh * 4 + (jj >> 5)) * 128 * kBins + k0;
        char* nb = smem + bw * 49152;
        #pragma unroll
        for (int i = 0; i < 4; i++)
            __builtin_amdgcn_global_load_lds((gsrc_t*)(srcA[i] + k0), (gdst_t*)(nb + dstA[i]), 16, 0, 0);
        #pragma unroll
        for (int i = 0; i < 2; i++)
            __builtin_amdgcn_global_load_lds((gsrc_t*)(srcB[i] + etoff), (gdst_t*)(nb + dstB[i]), 16, 0, 0);
    };

    __syncthreads();

    issue(0, 0);
    issue(1, 1);
    int bread = 0, bwrite = 2;

    #pragma unroll 1
    for (int et = 0; et < 4; et++) {
        f32x4 hi[4][4], lo[4][4];
        #pragma unroll
        for (int mi = 0; mi < 4; mi++)
            #pragma unroll
            for (int ei = 0; ei < 4; ei++) {
                hi[mi][ei] = (f32x4){0.f, 0.f, 0.f, 0.f};
                lo[mi][ei] = (f32x4){0.f, 0.f, 0.f, 0.f};
            }

        #pragma unroll 1
        for (int ks = 0; ks < 32; ks++) {
            const int j = et * 32 + ks;
            if (j < 127)
                asm volatile("s_waitcnt vmcnt(6)\n\ts_barrier" ::: "memory");
            else
                asm volatile("s_waitcnt vmcnt(0)\n\ts_barrier" ::: "memory");
            if (j < 126) {
                issue(j + 2, bwrite);
                bwrite = (bwrite == 2) ? 0 : bwrite + 1;
            }

            const char* buf = smem + bread * 49152;
            bread = (bread == 2) ? 0 : bread + 1;

            f16x8 a1[4], a2[4], b1f[4], b2f[4];
            #pragma unroll
            for (int mi = 0; mi < 4; mi++) {
                a1[mi] = *(const f16x8*)(buf + baseA1 + mi * 2048);
                a2[mi] = *(const f16x8*)(buf + baseA2 + mi * 2048);
            }
            #pragma unroll
            for (int ei = 0; ei < 4; ei++) {
                b1f[ei] = *(const f16x8*)(buf + baseB1 + ei * 2048);
                b2f[ei] = *(const f16x8*)(buf + baseB2 + ei * 2048);
            }
            __builtin_amdgcn_s_setprio(1);
            #pragma unroll
            for (int mi = 0; mi < 4; mi++)
                #pragma unroll
                for (int ei = 0; ei < 4; ei++) {
                    hi[mi][ei] = __builtin_amdgcn_mfma_f32_16x16x32_f16(a1[mi], b1f[ei], hi[mi][ei], 0, 0, 0);
                    lo[mi][ei] = __builtin_amdgcn_mfma_f32_16x16x32_f16(a1[mi], b2f[ei], lo[mi][ei], 0, 0, 0);
                    lo[mi][ei] = __builtin_amdgcn_mfma_f32_16x16x32_f16(a2[mi], b1f[ei], lo[mi][ei], 0, 0, 0);
                }
            __builtin_amdgcn_s_setprio(0);
        }

        #pragma unroll
        for (int ei = 0; ei < 4; ei++) {
            const int eloc = et * 128 + we * 64 + ei * 16 + l15;
            const float ev = lds_e2[eloc];
            const int eix = eh * 512 + eloc;
            #pragma unroll
            for (int mi = 0; mi < 4; mi++) {
                f32x4 dot4 = hi[mi][ei] + lo[mi][ei] * (1.0f / 4096.0f);
                #pragma unroll
                for (int rr = 0; rr < 4; rr++) {
                    float d = ev - 2.0f * dot4[rr];
                    int s = mi * 4 + rr;
                    if (d < rm[s]) { rm[s] = d; ri[s] = eix; }
                }
            }
        }
    }

    #pragma unroll
    for (int m = 1; m < 16; m <<= 1) {
        #pragma unroll
        for (int s = 0; s < 16; s++) {
            float ov = __shfl_xor(rm[s], m);
            int oi = __shfl_xor(ri[s], m);
            if (ov < rm[s] || (ov == rm[s] && oi < ri[s])) { rm[s] = ov; ri[s] = oi; }
        }
    }

    float* mv = (float*)smem;           // [256][2]
    int* miv = (int*)(smem + 2048);     // [256][2]
    __syncthreads();
    if (l15 == 0) {
        #pragma unroll
        for (int s = 0; s < 16; s++) {
            int mi = s >> 2, rr = s & 3;
            int rloc = wm * 64 + mi * 16 + (lane >> 4) * 4 + rr;
            mv[rloc * 2 + we] = rm[s];
            miv[rloc * 2 + we] = ri[s];
        }
    }
    __syncthreads();
    if (t < 256) {
        float v0 = mv[t * 2], v1 = mv[t * 2 + 1];
        int i0 = miv[t * 2], i1 = miv[t * 2 + 1];
        bool take1 = (v1 < v0) || (v1 == v0 && i1 < i0);
        float bv = take1 ? v1 : v0;
        int bi = take1 ? i1 : i0;
        unsigned int u = __float_as_uint(bv);
        unsigned int su = (u & 0x80000000u) ? ~u : (u ^ 0x80000000u);
        unsigned long long packed = ((unsigned long long)su << 32) | (unsigned int)bi;
        atomicMin(&pk[ch * kN + n0 + t], packed);
    }
}

// ================= gather (cp-XCD affine) + fused loss =====================
__global__ __launch_bounds__(256) void gather_pk(
    const float* __restrict__ cb, const unsigned long long* __restrict__ pk,
    const float* __restrict__ partials, float* __restrict__ out,
    float* __restrict__ loss)
{
    const int t = threadIdx.x;
    const int lane = t & 63, q = t >> 6;
    const int b = blockIdx.x;
    const int cp = b & 7;
    const int bt = (b >> 3) & 63;
    const int ftile = (b >> 9) & 7;
    const int bb = b >> 12;
    const int co = (kC - 1) - cp;
    const int f = ftile * 64 + lane;
    const int n = bb * kFrames + f;
    const int e = (int)(unsigned int)(pk[cp * kN + n] & 0xFFFFFFFFull);
    const int bin0 = bt * 16 + q * 4;
    const float4 v4 = *(const float4*)&cb[((size_t)cp * kE + e) * kBins + bin0];
    const size_t base = ((size_t)(bb * kC + co) * kBins + bin0) * kFrames + f;
    out[base] = v4.x;
    out[base + kFrames] = v4.y;
    out[base + 2 * (size_t)kFrames] = v4.z;
    out[base + 3 * (size_t)kFrames] = v4.w;

    if (b == 32767) {
        __shared__ float reds[256];
        float s = 0.f;
        for (int i = t; i < kC * kN; i += 256) {
            unsigned int su = (unsigned int)(pk[i] >> 32);
            unsigned int u = (su & 0x80000000u) ? (su ^ 0x80000000u) : ~su;
            s += __uint_as_float(u);
        }
        for (int i = t; i < 4096; i += 256) s += partials[i];
        reds[t] = s;
        __syncthreads();
        for (int off = 128; off > 0; off >>= 1) {
            if (t < off) reds[t] += reds[t + off];
            __syncthreads();
        }
        if (t == 0) loss[0] = 1.25f * reds[0] / (float)(kN * kBins);
    }
}

} // namespace

extern "C" void kernel_launch(void* const* d_in, const int* in_sizes, int n_in,
                              void* d_out, int out_size, void* d_ws, size_t ws_size,
                              hipStream_t stream)
{
    const float* x   = (const float*)d_in[0];
    const float* w1  = (const float*)d_in[1];
    const float* b1  = (const float*)d_in[2];
    const float* w2  = (const float*)d_in[3];
    const float* b2  = (const float*)d_in[4];
    const float* wsk = (const float*)d_in[5];
    const float* bsk = (const float*)d_in[6];
    const float* cb  = (const float*)d_in[7];
    float* out = (float*)d_out;
    char* ws = (char*)d_ws;

    // ws layout: B1|B2 32M | e2 32K | pk 256K | partials 16K
    _Float16* B1 = (_Float16*)ws;
    float* e2                  = (float*)(ws + 33554432);
    unsigned long long* pk     = (unsigned long long*)(ws + 33554432 + 32768);
    float* partials            = (float*)(ws + 33554432 + 32768 + 262144);
    _Float16* V1 = (_Float16*)d_out; // V1 67MB | V2 67MB, overwritten by gather

    conv_fused_v2c<<<dim3(kBins / BT, kFrames / FT, kB), 512, 0, stream>>>(
        x, w1, b1, w2, b2, wsk, bsk, V1, partials);
    cbsplit_e2<<<(kC * kE) / 4, 256, 0, stream>>>(cb, B1, e2, pk);
    dist_mfma<<<dim3(256), 512, 0, stream>>>(V1, B1, e2, pk);
    gather_pk<<<dim3(32768), 256, 0, stream>>>(cb, pk, partials, out,
                                               out + (size_t)kC * kBins * kN);
}

// Round 13
// 390.002 us; speedup vs baseline: 1.0583x; 1.0544x over previous
//
#include <hip/hip_runtime.h>

namespace {

constexpr int kB = 8, kCin = 2, kBins = 1024, kFrames = 512;
constexpr int kC = 8, kE = 1024, kN = kB * kFrames; // 4096

typedef _Float16 f16x8 __attribute__((ext_vector_type(8)));
typedef float f32x4 __attribute__((ext_vector_type(4)));

union HPack4 { _Float16 h[4]; uint2 u; };
union HPack2 { _Float16 h[2]; unsigned int u; };

// split v = h + (l/4096), h/l normal-range f16 (denormal-proof)
__device__ inline void splitf(float v, _Float16& h, _Float16& l) {
    float a = (fabsf(v) >= 6.103515625e-05f) ? v : 0.f;
    _Float16 hh = (_Float16)a;
    h = hh;
    l = (_Float16)((v - (float)hh) * 4096.0f);
}

// ================= conv v2d: v2c compute + ping-pong retile ================
// v2c's arithmetic verbatim (v bit-identical). Stores now go through a
// ping-pong LDS vbuf so lane index = k (fast axis of V): 16 consecutive
// lanes cover each 64B line (4 fully-covered lines per wave-store) vs the
// previous 64-line scatter. 1 barrier per channel (ping-pong WAR-safe).
constexpr int BT = 32, FT = 32, XB = BT + 16, HB = BT + 8;

__global__ __launch_bounds__(512, 4) void conv_fused_v2d(
    const float* __restrict__ x,
    const float* __restrict__ w1, const float* __restrict__ b1,
    const float* __restrict__ w2, const float* __restrict__ b2,
    const float* __restrict__ wsk, const float* __restrict__ bsk,
    _Float16* __restrict__ V1, float* __restrict__ partials)
{
    __shared__ float xt[kCin][XB][33];
    __shared__ float h1t[kC][HB][33];
    __shared__ float vbuf[2][BT][33];
    __shared__ float w1s[kC * kCin * 9];
    __shared__ float w2s[kC * kC][12];
    __shared__ float wsks[kC * kCin];
    __shared__ float b1s[kC], b2s[kC], bsks[kC];
    __shared__ float reds[8];

    const int t = threadIdx.x;
    const int bt = blockIdx.x, ft = blockIdx.y, bb = blockIdx.z;
    const int bs = bt * BT, f0 = ft * FT;
    _Float16* V2 = V1 + (size_t)33554432;

    if (t < kC * kCin * 9) w1s[t] = w1[t];
    for (int i = t; i < 768; i += 512) {
        int cc = i / 12, k = i % 12;
        w2s[cc][k] = (k < 9) ? w2[cc * 9 + k] : 0.f;
    }
    if (t < kC * kCin) wsks[t] = wsk[t];
    if (t < kC) { b1s[t] = b1[t]; b2s[t] = b2[t]; bsks[t] = bsk[t]; }

    // stage x tile [bs-8, bs+40)
    for (int i = t; i < kCin * XB * FT; i += 512) {
        int fi = i % FT, xb = (i / FT) % XB, ci = i / (FT * XB);
        int gb = bs - 8 + xb;
        float v = 0.f;
        if (gb >= 0 && gb < kBins)
            v = x[((bb * kCin + ci) * kBins + gb) * kFrames + f0 + fi];
        xt[ci][xb][fi] = v;
    }
    __syncthreads();

    const int fi = t & 31;
    const int r = t >> 5;          // 0..15
    const int cm = r & 7, rh = r >> 3;  // rh wave-uniform

    // h1 stage: octets q in {0,2,4} for rh=0, {1,3} for rh=1
    #pragma unroll
    for (int qi = 0; qi < 3; qi++) {
        const int q = qi * 2 + rh;
        if (q < 5) {
            float a8[8];
            #pragma unroll
            for (int jj = 0; jj < 8; jj++) a8[jj] = b1s[cm];
            #pragma unroll
            for (int ci = 0; ci < kCin; ci++) {
                float w[16];
                #pragma unroll
                for (int k = 0; k < 16; k++) w[k] = xt[ci][q * 8 + k][fi];
                const float* wp = &w1s[(cm * kCin + ci) * 9];
                #pragma unroll
                for (int jj = 0; jj < 8; jj++)
                    #pragma unroll
                    for (int k = 0; k < 9; k++)
                        a8[jj] += w[jj + k] * wp[k];
            }
            #pragma unroll
            for (int jj = 0; jj < 8; jj++) {
                int hb = q * 8 + jj;
                int gb = bs - 4 + hb;
                float v = (gb >= 0 && gb < kBins) ? (a8[jj] > 0.f ? a8[jj] : 0.2f * a8[jj]) : 0.f;
                h1t[cm][hb][fi] = v;
            }
        }
    }
    __syncthreads();

    // main stage (verbatim v2c): thread (fi, r) -> 8 c x 2 bins (ob = r*2+j)
    float acc[8][2];
    #pragma unroll
    for (int c = 0; c < 8; c++)
        #pragma unroll
        for (int j = 0; j < 2; j++) acc[c][j] = b2s[c] + bsks[c];

    for (int ci = 0; ci < 8; ci++) {
        float w[10];
        #pragma unroll
        for (int k = 0; k < 10; k++) w[k] = h1t[ci][r * 2 + k][fi];
        #pragma unroll
        for (int c = 0; c < 8; c++) {
            const float4* wp4 = (const float4*)&w2s[c * 8 + ci][0];
            float4 wA = wp4[0], wB = wp4[1], wC = wp4[2];
            float wk[9] = {wA.x, wA.y, wA.z, wA.w, wB.x, wB.y, wB.z, wB.w, wC.x};
            #pragma unroll
            for (int j = 0; j < 2; j++) {
                float s = 0.f;
                #pragma unroll
                for (int k = 0; k < 9; k++) s += w[j + k] * wk[k];
                acc[c][j] += s;
            }
        }
    }
    // skip path
    #pragma unroll
    for (int j = 0; j < 2; j++) {
        float x0 = xt[0][r * 2 + j + 8][fi];
        float x1 = xt[1][r * 2 + j + 8][fi];
        #pragma unroll
        for (int c = 0; c < 8; c++)
            acc[c][j] += x0 * wsks[c * 2] + x1 * wsks[c * 2 + 1];
    }

    float sq = 0.f;
    #pragma unroll
    for (int c = 0; c < 8; c++)
        #pragma unroll
        for (int j = 0; j < 2; j++) sq += acc[c][j] * acc[c][j];

    // ping-pong retile + coalesced stores: thread (rn = t>>4, kq = t&15)
    // reads bins [kq*2, kq*2+1] of n-row rn; 16 lanes cover a 64B line.
    const int rn = t >> 4, kq = t & 15;
    #pragma unroll 1
    for (int c = 0; c < 8; c++) {
        vbuf[c & 1][fi][r * 2 + 0] = acc[c][0];
        vbuf[c & 1][fi][r * 2 + 1] = acc[c][1];
        __syncthreads();
        float v0 = vbuf[c & 1][rn][kq * 2 + 0];
        float v1 = vbuf[c & 1][rn][kq * 2 + 1];
        HPack2 ph, pl;
        splitf(v0, ph.h[0], pl.h[0]);
        splitf(v1, ph.h[1], pl.h[1]);
        const int ng = bb * kFrames + f0 + rn;
        const size_t off = ((size_t)(c * kN + ng)) * kBins + bs + kq * 2;
        *(unsigned int*)&V1[off] = ph.u;
        *(unsigned int*)&V2[off] = pl.u;
    }

    // per-block sum(v^2): wave shfl-reduce, then 8-way LDS merge
    #pragma unroll
    for (int off = 32; off > 0; off >>= 1) sq += __shfl_down(sq, off);
    if ((t & 63) == 0) reds[t >> 6] = sq;
    __syncthreads();
    if (t == 0) {
        float s = 0.f;
        #pragma unroll
        for (int i = 0; i < 8; i++) s += reds[i];
        int blin = (bb * gridDim.y + blockIdx.y) * gridDim.x + blockIdx.x;
        partials[blin] = s;
    }
}

// ================= codebook split + e2 (+ pk init) =================
__global__ __launch_bounds__(256) void cbsplit_e2(
    const float* __restrict__ cb, _Float16* __restrict__ B1,
    float* __restrict__ e2, unsigned long long* __restrict__ pk)
{
    const int gid = blockIdx.x * 256 + threadIdx.x;
    if (gid < kC * kN) pk[gid] = ~0ull;

    const int gw = gid >> 6;
    const int lane = threadIdx.x & 63;
    _Float16* B2 = B1 + (size_t)8388608;
    const float* row = cb + (size_t)gw * kBins;
    float s = 0.f;
    #pragma unroll
    for (int j = 0; j < 4; j++) {
        float4 v = *(const float4*)&row[lane * 4 + j * 256];
        s += v.x * v.x + v.y * v.y + v.z * v.z + v.w * v.w;
        HPack4 ph, pl;
        splitf(v.x, ph.h[0], pl.h[0]);
        splitf(v.y, ph.h[1], pl.h[1]);
        splitf(v.z, ph.h[2], pl.h[2]);
        splitf(v.w, ph.h[3], pl.h[3]);
        size_t off = (size_t)gw * kBins + lane * 4 + j * 256;
        *(uint2*)&B1[off] = ph.u;
        *(uint2*)&B2[off] = pl.u;
    }
    #pragma unroll
    for (int off = 32; off > 0; off >>= 1) s += __shfl_down(s, off);
    if (lane == 0) e2[gw] = s;
}

// ================= MFMA distance + argmin (r10-proven, verbatim) ===========
__global__ __launch_bounds__(512, 2) void dist_mfma(
    const _Float16* __restrict__ V1, const _Float16* __restrict__ B1p,
    const float* __restrict__ e2, unsigned long long* __restrict__ pk)
{
    __shared__ char smem[3 * 49152 + 2048];

    const int t = threadIdx.x;
    const int bidx = blockIdx.x;
    const int ch = bidx & 7;
    const int eh = (bidx >> 3) & 1;
    const int n0 = (bidx >> 4) * 256;
    const int w = t >> 6, lane = t & 63;
    const int l15 = lane & 15, kc4 = lane >> 4;
    const int wm = w >> 1, we = w & 1;

    float* lds_e2 = (float*)(smem + 147456);
    lds_e2[t] = e2[ch * kE + eh * 512 + t];

    const _Float16* srcA[4];
    int dstA[4];
    #pragma unroll
    for (int i = 0; i < 4; i++) {
        int ci = i * 512 + t;
        int row = ci >> 3, slot = ci & 7;
        int g = slot ^ (row & 7);
        int p = g >> 2, kc = g & 3;
        srcA[i] = V1 + (size_t)p * 33554432 + ((size_t)(ch * kN + n0 + row)) * kBins + kc * 8;
        dstA[i] = ci * 16;
    }
    const _Float16* srcB[2];
    int dstB[2];
    #pragma unroll
    for (int i = 0; i < 2; i++) {
        int bi = i * 512 + t;
        int row = bi >> 3, slot = bi & 7;
        int g = slot ^ (row & 7);
        int p = g >> 2, kc = g & 3;
        srcB[i] = B1p + (size_t)p * 8388608 + ((size_t)(ch * kE + row)) * kBins + kc * 8;
        dstB[i] = 32768 + bi * 16;
    }

    const int rowA = wm * 64 + l15;
    const int rowB = we * 64 + l15;
    const int baseA1 = rowA * 128 + ((kc4) ^ (rowA & 7)) * 16;
    const int baseA2 = rowA * 128 + ((4 + kc4) ^ (rowA & 7)) * 16;
    const int baseB1 = 32768 + rowB * 128 + ((kc4) ^ (rowB & 7)) * 16;
    const int baseB2 = 32768 + rowB * 128 + ((4 + kc4) ^ (rowB & 7)) * 16;

    float rm[16];
    int ri[16];
    #pragma unroll
    for (int s = 0; s < 16; s++) { rm[s] = 3.4e38f; ri[s] = 0; }

    typedef const __attribute__((address_space(1))) void gsrc_t;
    typedef __attribute__((address_space(3))) void gdst_t;

    auto issue = [&](int jj, int bw) {
        const int k0 = (jj & 31) * 32;
        const size_t etoff = (size_t)(eh * 4 + (jj >> 5)) * 128 * kBins + k0;
        char* nb = smem + bw * 49152;
        #pragma unroll
        for (int i = 0; i < 4; i++)
            __builtin_amdgcn_global_load_lds((gsrc_t*)(srcA[i] + k0), (gdst_t*)(nb + dstA[i]), 16, 0, 0);
        #pragma unroll
        for (int i = 0; i < 2; i++)
            __builtin_amdgcn_global_load_lds((gsrc_t*)(srcB[i] + etoff), (gdst_t*)(nb + dstB[i]), 16, 0, 0);
    };

    __syncthreads();

    issue(0, 0);
    issue(1, 1);
    int bread = 0, bwrite = 2;

    #pragma unroll 1
    for (int et = 0; et < 4; et++) {
        f32x4 hi[4][4], lo[4][4];
        #pragma unroll
        for (int mi = 0; mi < 4; mi++)
            #pragma unroll
            for (int ei = 0; ei < 4; ei++) {
                hi[mi][ei] = (f32x4){0.f, 0.f, 0.f, 0.f};
                lo[mi][ei] = (f32x4){0.f, 0.f, 0.f, 0.f};
            }

        #pragma unroll 1
        for (int ks = 0; ks < 32; ks++) {
            const int j = et * 32 + ks;
            if (j < 127)
                asm volatile("s_waitcnt vmcnt(6)\n\ts_barrier" ::: "memory");
            else
                asm volatile("s_waitcnt vmcnt(0)\n\ts_barrier" ::: "memory");
            if (j < 126) {
                issue(j + 2, bwrite);
                bwrite = (bwrite == 2) ? 0 : bwrite + 1;
            }

            const char* buf = smem + bread * 49152;
            bread = (bread == 2) ? 0 : bread + 1;

            f16x8 a1[4], a2[4], b1f[4], b2f[4];
            #pragma unroll
            for (int mi = 0; mi < 4; mi++) {
                a1[mi] = *(const f16x8*)(buf + baseA1 + mi * 2048);
                a2[mi] = *(const f16x8*)(buf + baseA2 + mi * 2048);
            }
            #pragma unroll
            for (int ei = 0; ei < 4; ei++) {
                b1f[ei] = *(const f16x8*)(buf + baseB1 + ei * 2048);
                b2f[ei] = *(const f16x8*)(buf + baseB2 + ei * 2048);
            }
            __builtin_amdgcn_s_setprio(1);
            #pragma unroll
            for (int mi = 0; mi < 4; mi++)
                #pragma unroll
                for (int ei = 0; ei < 4; ei++) {
                    hi[mi][ei] = __builtin_amdgcn_mfma_f32_16x16x32_f16(a1[mi], b1f[ei], hi[mi][ei], 0, 0, 0);
                    lo[mi][ei] = __builtin_amdgcn_mfma_f32_16x16x32_f16(a1[mi], b2f[ei], lo[mi][ei], 0, 0, 0);
                    lo[mi][ei] = __builtin_amdgcn_mfma_f32_16x16x32_f16(a2[mi], b1f[ei], lo[mi][ei], 0, 0, 0);
                }
            __builtin_amdgcn_s_setprio(0);
        }

        #pragma unroll
        for (int ei = 0; ei < 4; ei++) {
            const int eloc = et * 128 + we * 64 + ei * 16 + l15;
            const float ev = lds_e2[eloc];
            const int eix = eh * 512 + eloc;
            #pragma unroll
            for (int mi = 0; mi < 4; mi++) {
                f32x4 dot4 = hi[mi][ei] + lo[mi][ei] * (1.0f / 4096.0f);
                #pragma unroll
                for (int rr = 0; rr < 4; rr++) {
                    float d = ev - 2.0f * dot4[rr];
                    int s = mi * 4 + rr;
                    if (d < rm[s]) { rm[s] = d; ri[s] = eix; }
                }
            }
        }
    }

    #pragma unroll
    for (int m = 1; m < 16; m <<= 1) {
        #pragma unroll
        for (int s = 0; s < 16; s++) {
            float ov = __shfl_xor(rm[s], m);
            int oi = __shfl_xor(ri[s], m);
            if (ov < rm[s] || (ov == rm[s] && oi < ri[s])) { rm[s] = ov; ri[s] = oi; }
        }
    }

    float* mv = (float*)smem;           // [256][2]
    int* miv = (int*)(smem + 2048);     // [256][2]
    __syncthreads();
    if (l15 == 0) {
        #pragma unroll
        for (int s = 0; s < 16; s++) {
            int mi = s >> 2, rr = s & 3;
            int rloc = wm * 64 + mi * 16 + (lane >> 4) * 4 + rr;
            mv[rloc * 2 + we] = rm[s];
            miv[rloc * 2 + we] = ri[s];
        }
    }
    __syncthreads();
    if (t < 256) {
        float v0 = mv[t * 2], v1 = mv[t * 2 + 1];
        int i0 = miv[t * 2], i1 = miv[t * 2 + 1];
        bool take1 = (v1 < v0) || (v1 == v0 && i1 < i0);
        float bv = take1 ? v1 : v0;
        int bi = take1 ? i1 : i0;
        unsigned int u = __float_as_uint(bv);
        unsigned int su = (u & 0x80000000u) ? ~u : (u ^ 0x80000000u);
        unsigned long long packed = ((unsigned long long)su << 32) | (unsigned int)bi;
        atomicMin(&pk[ch * kN + n0 + t], packed);
    }
}

// ================= gather (cp-XCD affine) + fused loss =====================
__global__ __launch_bounds__(256) void gather_pk(
    const float* __restrict__ cb, const unsigned long long* __restrict__ pk,
    const float* __restrict__ partials, float* __restrict__ out,
    float* __restrict__ loss)
{
    const int t = threadIdx.x;
    const int lane = t & 63, q = t >> 6;
    const int b = blockIdx.x;
    const int cp = b & 7;
    const int bt = (b >> 3) & 63;
    const int ftile = (b >> 9) & 7;
    const int bb = b >> 12;
    const int co = (kC - 1) - cp;
    const int f = ftile * 64 + lane;
    const int n = bb * kFrames + f;
    const int e = (int)(unsigned int)(pk[cp * kN + n] & 0xFFFFFFFFull);
    const int bin0 = bt * 16 + q * 4;
    const float4 v4 = *(const float4*)&cb[((size_t)cp * kE + e) * kBins + bin0];
    const size_t base = ((size_t)(bb * kC + co) * kBins + bin0) * kFrames + f;
    out[base] = v4.x;
    out[base + kFrames] = v4.y;
    out[base + 2 * (size_t)kFrames] = v4.z;
    out[base + 3 * (size_t)kFrames] = v4.w;

    if (b == 32767) {
        __shared__ float reds[256];
        float s = 0.f;
        for (int i = t; i < kC * kN; i += 256) {
            unsigned int su = (unsigned int)(pk[i] >> 32);
            unsigned int u = (su & 0x80000000u) ? (su ^ 0x80000000u) : ~su;
            s += __uint_as_float(u);
        }
        for (int i = t; i < 4096; i += 256) s += partials[i];
        reds[t] = s;
        __syncthreads();
        for (int off = 128; off > 0; off >>= 1) {
            if (t < off) reds[t] += reds[t + off];
            __syncthreads();
        }
        if (t == 0) loss[0] = 1.25f * reds[0] / (float)(kN * kBins);
    }
}

} // namespace

extern "C" void kernel_launch(void* const* d_in, const int* in_sizes, int n_in,
                              void* d_out, int out_size, void* d_ws, size_t ws_size,
                              hipStream_t stream)
{
    const float* x   = (const float*)d_in[0];
    const float* w1  = (const float*)d_in[1];
    const float* b1  = (const float*)d_in[2];
    const float* w2  = (const float*)d_in[3];
    const float* b2  = (const float*)d_in[4];
    const float* wsk = (const float*)d_in[5];
    const float* bsk = (const float*)d_in[6];
    const float* cb  = (const float*)d_in[7];
    float* out = (float*)d_out;
    char* ws = (char*)d_ws;

    // ws layout: B1|B2 32M | e2 32K | pk 256K | partials 16K
    _Float16* B1 = (_Float16*)ws;
    float* e2                  = (float*)(ws + 33554432);
    unsigned long long* pk     = (unsigned long long*)(ws + 33554432 + 32768);
    float* partials            = (float*)(ws + 33554432 + 32768 + 262144);
    _Float16* V1 = (_Float16*)d_out; // V1 67MB | V2 67MB, overwritten by gather

    conv_fused_v2d<<<dim3(kBins / BT, kFrames / FT, kB), 512, 0, stream>>>(
        x, w1, b1, w2, b2, wsk, bsk, V1, partials);
    cbsplit_e2<<<(kC * kE) / 4, 256, 0, stream>>>(cb, B1, e2, pk);
    dist_mfma<<<dim3(256), 512, 0, stream>>>(V1, B1, e2, pk);
    gather_pk<<<dim3(32768), 256, 0, stream>>>(cb, pk, partials, out,
                                               out + (size_t)kC * kBins * kN);
}